// Round 18
// baseline (492.526 us; speedup 1.0000x reference)
//
#include <hip/hip_runtime.h>

// Demosaic BG-Bayer (top-left red) -> RGB, closed-form stencil.
// Round-8 restructure: PERSISTENT THREADS + batch-image pipeline.
// 2048 blocks x 256 thr = 524288 threads = exactly the 2x4 tiles of ONE image.
// Each thread keeps its (row-pair, strip) tile and iterates over the 8 batch
// images, prefetching image k+1's four input rows while computing image k.
// Rationale: rounds 0/4/7 showed cache-path tweaks (XCD swizzle, shuffle edge
// exchange, nt stores) all neutral at ~225us kernel time (~2.4 TB/s effective
// vs 6.3 achievable) -> suspect per-wave latency exposure of one-shot waves.

#define HH 2048
#define WW 2048
#define NIMG 8

__global__ __launch_bounds__(256) void demosaic_bg_kernel(const float* __restrict__ in,
                                                          float* __restrict__ out) {
    const size_t IMG   = (size_t)HH * WW;      // input image stride (floats)
    const size_t PLANE = (size_t)HH * WW;      // output plane stride
    const size_t OIMG  = 3 * PLANE;            // output image stride

    // bijective XCD-contiguous remap (2048 blocks, 8 XCDs -> 256 blocks each)
    int bid = (int)blockIdx.x;
    int nb = (bid & 7) * ((int)gridDim.x >> 3) + (bid >> 3);
    int gid = nb * 256 + (int)threadIdx.x;

    int s  = gid & 511;          // strip in row (512 strips of 4 cols)
    int yp = gid >> 9;           // row pair 0..1023
    int y  = yp << 1;            // even row
    int x0 = s << 2;
    int lane = (int)threadIdx.x & 63;

    const int i0 = (y == 0) ? 1 : y - 1;
    const int i3 = (y + 2 > HH - 2) ? (HH - 2) : y + 2;

    // row pointers for image 0, pre-offset by x0
    const float* pa = in + (size_t)i0 * WW + x0;
    const float* pb = in + (size_t)y * WW + x0;
    const float* pc = in + (size_t)(y + 1) * WW + x0;
    const float* pd = in + (size_t)i3 * WW + x0;
    float* op = out + (size_t)y * WW + x0;

    const bool lz  = (lane == 0);
    const bool l63 = (lane == 63);
    const bool xlo = (x0 == 0);
    const bool xhi = (x0 + 4 > WW - 2);   // x0 == 2044

    float4 a = *(const float4*)pa;
    float4 b = *(const float4*)pb;
    float4 c = *(const float4*)pc;
    float4 d = *(const float4*)pd;

#pragma unroll
    for (int k = 0; k < NIMG; ++k) {
        // ---- prefetch image k+1 (hidden under this image's compute) ----
        float4 fa, fb, fc, fd;
        if (k + 1 < NIMG) {
            fa = *(const float4*)(pa + IMG);
            fb = *(const float4*)(pb + IMG);
            fc = *(const float4*)(pc + IMG);
            fd = *(const float4*)(pd + IMG);
        }

        // ---- in-wave edge exchange for current image ----
        float la = __shfl_up(a.w, 1);
        float lb = __shfl_up(b.w, 1);
        float lc = __shfl_up(c.w, 1);
        float rb = __shfl_down(b.x, 1);
        float rc = __shfl_down(c.x, 1);
        float rd = __shfl_down(d.x, 1);

        if (lz) {
            if (xlo) { la = a.y; lb = b.y; lc = c.y; }
            else     { la = pa[-1]; lb = pb[-1]; lc = pc[-1]; }
        }
        if (l63) {
            if (xhi) { rb = b.z; rc = c.z; rd = d.z; }
            else     { rb = pb[4]; rc = pc[4]; rd = pd[4]; }
        }

        // ---- even output row y: [red, green, red, green] ----
        float4 Re, Ge, Be;
        Re.x = b.x;
        Ge.x = 0.25f * (a.x + c.x + lb + b.y);
        Be.x = 0.25f * (la + a.y + lc + c.y);

        Re.y = 0.5f * (b.x + b.z);
        Ge.y = b.y;
        Be.y = 0.5f * (a.y + c.y);

        Re.z = b.z;
        Ge.z = 0.25f * (a.z + c.z + b.y + b.w);
        Be.z = 0.25f * (a.y + a.w + c.y + c.w);

        Re.w = 0.5f * (b.z + rb);
        Ge.w = b.w;
        Be.w = 0.5f * (a.w + c.w);

        // ---- odd output row y+1: [green, blue, green, blue] ----
        float4 Ro, Go, Bo;
        Ro.x = 0.5f * (b.x + d.x);
        Go.x = c.x;
        Bo.x = 0.5f * (lc + c.y);

        Ro.y = 0.25f * (b.x + b.z + d.x + d.z);
        Go.y = 0.25f * (b.y + d.y + c.x + c.z);
        Bo.y = c.y;

        Ro.z = 0.5f * (b.z + d.z);
        Go.z = c.z;
        Bo.z = 0.5f * (c.y + c.w);

        Ro.w = 0.25f * (b.z + rb + d.z + rd);
        Go.w = 0.25f * (b.w + d.w + c.z + rc);
        Bo.w = c.w;

        *(float4*)(op)                  = Re;
        *(float4*)(op + WW)             = Ro;
        *(float4*)(op + PLANE)          = Ge;
        *(float4*)(op + PLANE + WW)     = Go;
        *(float4*)(op + 2 * PLANE)      = Be;
        *(float4*)(op + 2 * PLANE + WW) = Bo;

        // ---- rotate to next image ----
        pa += IMG; pb += IMG; pc += IMG; pd += IMG; op += OIMG;
        if (k + 1 < NIMG) { a = fa; b = fb; c = fc; d = fd; }
    }
}

extern "C" void kernel_launch(void* const* d_in, const int* in_sizes, int n_in,
                              void* d_out, int out_size, void* d_ws, size_t ws_size,
                              hipStream_t stream) {
    const float* in = (const float*)d_in[0];
    float* out = (float*)d_out;
    dim3 block(256);
    dim3 grid((HH / 2) * (WW / 4) / 256);   // 2048 blocks = 1 image of tiles
    demosaic_bg_kernel<<<grid, block, 0, stream>>>(in, out);
}